// Round 13
// baseline (1151.233 us; speedup 1.0000x reference)
//
#include <hip/hip_runtime.h>
#include <hip/hip_bf16.h>
#include <stdint.h>

#define H 1024
#define BATCH 64
#define TSTEPS 64
#define VOCAB 32000

typedef __attribute__((ext_vector_type(8))) short bf16x8;
typedef __attribute__((ext_vector_type(4))) float f32x4;

__device__ __forceinline__ uint16_t f2b(float f) {
  union { float f; uint32_t u; } v; v.f = f;
  uint32_t u = v.u;
  return (uint16_t)((u + 0x7FFFu + ((u >> 16) & 1u)) >> 16);
}

__device__ __forceinline__ void g2l16(const uint16_t* g, uint16_t* l) {
  __builtin_amdgcn_global_load_lds((const __attribute__((address_space(1))) void*)(g),
                                   (__attribute__((address_space(3))) void*)(l), 16, 0, 0);
}

// ---- f32 -> bf16 cast (n4 = n/4) ----
__global__ void cast_bf16_kernel(const float* __restrict__ src, uint16_t* __restrict__ dst, int n4) {
  int i = blockIdx.x * blockDim.x + threadIdx.x;
  int stride = gridDim.x * blockDim.x;
  for (; i < n4; i += stride) {
    float4 f = ((const float4*)src)[i];
    union { uint16_t u[4]; uint64_t d; } o;
    o.u[0] = f2b(f.x); o.u[1] = f2b(f.y); o.u[2] = f2b(f.z); o.u[3] = f2b(f.w);
    ((uint64_t*)dst)[i] = o.d;
  }
}

// ---- embed + relu -> bf16, X[t*64+b][H] ----
__global__ void embed_kernel(const float* __restrict__ emb, const int* __restrict__ tgt,
                             uint16_t* __restrict__ X) {
  int i = blockIdx.x;            // 0..4095 = t*64+b
  int t = i >> 6, b = i & 63;
  int tok = (t == 0) ? 0 : tgt[b * TSTEPS + (t - 1)];
  const float4* src = (const float4*)(emb + (size_t)tok * H);
  uint64_t* dst = (uint64_t*)(X + (size_t)i * H);
  int k = threadIdx.x;           // 256 threads x 4 elems
  float4 f = src[k];
  union { uint16_t u[4]; uint64_t d; } o;
  o.u[0] = f2b(fmaxf(f.x, 0.f)); o.u[1] = f2b(fmaxf(f.y, 0.f));
  o.u[2] = f2b(fmaxf(f.z, 0.f)); o.u[3] = f2b(fmaxf(f.w, 0.f));
  dst[k] = o.d;
}

// ---- h0 init: cast enc_hidden to bf16 into Hsb[0] ----
__global__ void h0_kernel(const float* __restrict__ eh, uint16_t* __restrict__ hb0) {
  int i = blockIdx.x * blockDim.x + threadIdx.x;   // 16384 threads x 4
  float4 f = ((const float4*)eh)[i];
  union { uint16_t u[4]; uint64_t d; } o;
  o.u[0] = f2b(f.x); o.u[1] = f2b(f.y); o.u[2] = f2b(f.z); o.u[3] = f2b(f.w);
  ((uint64_t*)hb0)[i] = o.d;
}

// ---- gi GEMM: gi = relu(emb)@W_ih^T + b_ih, row-major [4096][3072] f32 ----
__global__ __launch_bounds__(256) void gi_gemm_kernel(
    const uint16_t* __restrict__ A,    // [4096][1024]
    const uint16_t* __restrict__ Bm,   // [3072][1024]
    const float* __restrict__ bias,    // [3072]
    float* __restrict__ out) {         // [4096][3072]
  __shared__ uint16_t lA[128 * 32];
  __shared__ uint16_t lB[128 * 32];
  const int tid = threadIdx.x;
  const int lane = tid & 63;
  const int w = tid >> 6;
  const int wr = w >> 1, wc = w & 1;
  int flat = blockIdx.y * 24 + blockIdx.x;       // 768 blocks
  int nf = (flat & 7) * 96 + (flat >> 3);        // XCD swizzle (768 % 8 == 0)
  const int m0 = (nf / 24) * 128;
  const int n0 = (nf % 24) * 128;

  f32x4 acc[4][4];
#pragma unroll
  for (int mi = 0; mi < 4; ++mi)
#pragma unroll
    for (int ni = 0; ni < 4; ++ni) acc[mi][ni] = (f32x4){0, 0, 0, 0};

  const int srow = w * 16 + (lane >> 2);
  const int scol = (lane & 3) * 8;

  for (int k0 = 0; k0 < 1024; k0 += 32) {
    __syncthreads();
    g2l16(A + (size_t)(m0 + srow) * 1024 + k0 + scol,       &lA[w * 512]);
    g2l16(A + (size_t)(m0 + 64 + srow) * 1024 + k0 + scol,  &lA[2048 + w * 512]);
    g2l16(Bm + (size_t)(n0 + srow) * 1024 + k0 + scol,      &lB[w * 512]);
    g2l16(Bm + (size_t)(n0 + 64 + srow) * 1024 + k0 + scol, &lB[2048 + w * 512]);
    __syncthreads();
    bf16x8 a[4], b[4];
#pragma unroll
    for (int mi = 0; mi < 4; ++mi)
      a[mi] = *(const bf16x8*)&lA[(wr * 64 + mi * 16 + (lane & 15)) * 32 + (lane >> 4) * 8];
#pragma unroll
    for (int ni = 0; ni < 4; ++ni)
      b[ni] = *(const bf16x8*)&lB[(wc * 64 + ni * 16 + (lane & 15)) * 32 + (lane >> 4) * 8];
#pragma unroll
    for (int mi = 0; mi < 4; ++mi)
#pragma unroll
      for (int ni = 0; ni < 4; ++ni)
        acc[mi][ni] = __builtin_amdgcn_mfma_f32_16x16x32_bf16(a[mi], b[ni], acc[mi][ni], 0, 0, 0);
  }

#pragma unroll
  for (int ni = 0; ni < 4; ++ni) {
    int v = n0 + wc * 64 + ni * 16 + (lane & 15);
    float bv = bias[v];
#pragma unroll
    for (int mi = 0; mi < 4; ++mi) {
#pragma unroll
      for (int r = 0; r < 4; ++r) {
        int row = m0 + wr * 64 + mi * 16 + (lane >> 4) * 4 + r;
        out[(size_t)row * 3072 + v] = acc[mi][ni][r] + bv;
      }
    }
  }
}

// ---- one GRU step, gh-only: 256 blocks x 64 threads (R4 proven shape) ----
__global__ __launch_bounds__(64) void step_kernel(
    const uint16_t* __restrict__ Whh_b,  // [3072][1024] bf16
    const float* __restrict__ gi,        // [4096][3072] f32 (incl b_ih)
    const float* __restrict__ b_hh,      // [3072]
    const float* __restrict__ h_cur,     // [64][1024] f32
    float* __restrict__ h_nxt,           // [64][1024] f32
    uint16_t* __restrict__ Hsb,          // [65][64][1024] bf16
    int t) {
  const int lane = threadIdx.x;
  const int l15 = lane & 15, kq = lane >> 4;
  const int rg = blockIdx.x >> 6, cs = blockIdx.x & 63;
  const int m0 = rg * 16, c0 = cs * 16;
  const int c = c0 + l15;

  float gr[4], gz[4], gn[4], hold[4];
#pragma unroll
  for (int r = 0; r < 4; ++r) {
    int m = m0 + kq * 4 + r;
    const float* gp = gi + (size_t)(t * 64 + m) * 3072;
    gr[r] = gp[c]; gz[r] = gp[1024 + c]; gn[r] = gp[2048 + c];
    hold[r] = h_cur[(size_t)m * 1024 + c];
  }

  const uint16_t* ap = Hsb + (size_t)(t * 64 + m0 + l15) * 1024 + kq * 8;
  const uint16_t* br = Whh_b + (size_t)(c) * 1024 + kq * 8;
  const uint16_t* bz = Whh_b + (size_t)(1024 + c) * 1024 + kq * 8;
  const uint16_t* bn = Whh_b + (size_t)(2048 + c) * 1024 + kq * 8;

  f32x4 ar = {0,0,0,0}, az = {0,0,0,0}, an = {0,0,0,0};
#pragma unroll
  for (int kk = 0; kk < 32; ++kk) {
    bf16x8 a = *(const bf16x8*)(ap + kk * 32);
    ar = __builtin_amdgcn_mfma_f32_16x16x32_bf16(a, *(const bf16x8*)(br + kk * 32), ar, 0, 0, 0);
    az = __builtin_amdgcn_mfma_f32_16x16x32_bf16(a, *(const bf16x8*)(bz + kk * 32), az, 0, 0, 0);
    an = __builtin_amdgcn_mfma_f32_16x16x32_bf16(a, *(const bf16x8*)(bn + kk * 32), an, 0, 0, 0);
  }

  float bhr = b_hh[c], bhz = b_hh[1024 + c], bhn = b_hh[2048 + c];
#pragma unroll
  for (int r = 0; r < 4; ++r) {
    int m = m0 + kq * 4 + r;
    float rg_ = 1.f / (1.f + __expf(-(gr[r] + ar[r] + bhr)));
    float zg  = 1.f / (1.f + __expf(-(gz[r] + az[r] + bhz)));
    float ng  = tanhf(gn[r] + rg_ * (an[r] + bhn));
    float hnew = (1.f - zg) * ng + zg * hold[r];
    h_nxt[(size_t)m * 1024 + c] = hnew;
    Hsb[(size_t)((t + 1) * 64 + m) * 1024 + c] = f2b(hnew);
  }
}

// ============ 128x128 4-phase out-GEMM, 2 blocks/CU (T2+T3+T4+T5) ============
// 8 waves (2M x 4N), per-wave 64x32 (acc 32 VGPR), BK=64, 64 KiB LDS staging.
// Ledger: steady o: 2 ->ph0 4 ->ph1 6-vm(2)->2 ->ph2 4 ->ph3 6-vm(2)->2;
// peeled last iter drains with vm(0). Epilogue: CACHED scalar stores (L2 merges
// the 64B ni halves; NT caused +127MB partial-line amplification — R10).
// ssum lives at sm+0 (staging LDS is dead after the final barrier) — R12's
// fail was ssum at sm+65536 with only 65536 allocated (OOB into the
// co-resident block's LDS).

__device__ __forceinline__ void stageAH(const uint16_t* __restrict__ G, int grow0, int kt,
                                        char* lbase, int w, int l) {
#pragma unroll
  for (int j = 0; j < 2; ++j) {
    int c = w * 2 + j;
    int r = c * 8 + (l >> 3);
    int scol = ((l & 7) ^ (l >> 3)) * 8;   // pre-swizzled global col-slot
    g2l16(G + (size_t)(grow0 + r) * 1024 + kt * 64 + scol, (uint16_t*)(lbase + c * 1024));
  }
}

template<int AOFF, int BOFF, int MPH, bool RB>
__device__ __forceinline__ void ph_read(const char* sm, int wr, int wc, int l15, int kq,
                                        bf16x8 (&afr)[2][2], bf16x8 (&bfr)[2][2]) {
#pragma unroll
  for (int m = 0; m < 2; ++m) {
    const int mi = MPH * 2 + m;
    const int r = wr * 64 + mi * 16 + l15;
    const char* base = sm + AOFF + r * 128;
#pragma unroll
    for (int ks = 0; ks < 2; ++ks)
      afr[m][ks] = *(const bf16x8*)(base + ((((ks << 2) + kq) ^ (r & 7)) << 4));
  }
  if constexpr (RB) {
#pragma unroll
    for (int ni = 0; ni < 2; ++ni) {
      const int r = wc * 32 + ni * 16 + l15;
      const char* base = sm + BOFF + r * 128;
#pragma unroll
      for (int ks = 0; ks < 2; ++ks)
        bfr[ni][ks] = *(const bf16x8*)(base + ((((ks << 2) + kq) ^ (r & 7)) << 4));
    }
  }
}

template<int MPH>
__device__ __forceinline__ void ph_mma(f32x4 (&acc)[4][2], bf16x8 (&afr)[2][2], bf16x8 (&bfr)[2][2]) {
  __builtin_amdgcn_s_setprio(1);
#pragma unroll
  for (int m = 0; m < 2; ++m)
#pragma unroll
    for (int ni = 0; ni < 2; ++ni)
#pragma unroll
      for (int ks = 0; ks < 2; ++ks)
        acc[MPH * 2 + m][ni] =
            __builtin_amdgcn_mfma_f32_16x16x32_bf16(afr[m][ks], bfr[ni][ks], acc[MPH * 2 + m][ni], 0, 0, 0);
  __builtin_amdgcn_s_setprio(0);
}

// VM: 0 = no wait, 1 = vmcnt(2) (steady), 2 = vmcnt(0) (final drain)
#define PH(AOFF, BOFF, MPH, RB, STG, VM) { \
  bf16x8 afr[2][2]; \
  ph_read<AOFF, BOFF, MPH, RB>(sm, wr, wc, l15, kq, afr, bfr); \
  STG; \
  __builtin_amdgcn_sched_barrier(0); \
  if (VM == 1) asm volatile("s_waitcnt vmcnt(2)" ::: "memory"); \
  if (VM == 2) asm volatile("s_waitcnt vmcnt(0)" ::: "memory"); \
  __builtin_amdgcn_s_barrier(); \
  ph_mma<MPH>(acc, afr, bfr); \
  __builtin_amdgcn_s_barrier(); \
}

__global__ __launch_bounds__(512, 4) void out_gemm_kernel(
    const uint16_t* __restrict__ Ag,   // [4096][1024]  (Hsb+65536)
    const uint16_t* __restrict__ Bg,   // [32000][1024]
    const float* __restrict__ bias,    // [32000]
    float* __restrict__ out,
    float* __restrict__ px) {          // [4096][256] sum-exp per 128-col block
  extern __shared__ char sm[];
  const int tid = threadIdx.x;
  const int l = tid & 63, w = tid >> 6;
  const int l15 = l & 15, kq = l >> 4;
  const int wr = w >> 2, wc = w & 3;             // 2M x 4N waves
  // 2D-chunked XCD mapping: 8000 blocks, xcd owns 4 m-tiles, sweeps 250 n-tiles
  int flat = blockIdx.y * 1000 + blockIdx.x;
  int xcd = flat & 7, i0 = flat >> 3;            // i0 in 0..999
  const int m0 = ((xcd << 2) | (i0 & 3)) * 128;  // m-tile 0..31
  const int n0 = (i0 >> 2) * 128;                // n-tile 0..249

  char* const sA = sm;
  char* const sB = sm + 16384;
  char* const tA = sm + 32768;
  char* const tB = sm + 49152;

  f32x4 acc[4][2];
#pragma unroll
  for (int mi = 0; mi < 4; ++mi)
#pragma unroll
    for (int ni = 0; ni < 2; ++ni) acc[mi][ni] = (f32x4){0, 0, 0, 0};

  // prologue: kt0 {A,B} + kt1 {B}; kt1.A staged in ph0 of iter 0
  stageAH(Ag, m0, 0, sA, w, l);
  stageAH(Bg, n0, 0, sB, w, l);
  stageAH(Bg, n0, 1, tB, w, l);
  asm volatile("s_waitcnt vmcnt(2)" ::: "memory");   // kt0's 4 loads retired
  __builtin_amdgcn_s_barrier();

  bf16x8 bfr[2][2];
  for (int i = 0; i < 7; ++i) {                      // steady iters (kt 2i, 2i+1)
    PH(0,     16384, 0, true,  stageAH(Ag, m0, 2 * i + 1, tA, w, l), 0)
    PH(0,     16384, 1, false, stageAH(Bg, n0, 2 * i + 2, sB, w, l), 1)
    PH(32768, 49152, 0, true,  stageAH(Ag, m0, 2 * i + 2, sA, w, l), 0)
    PH(32768, 49152, 1, false, stageAH(Bg, n0, 2 * i + 3, tB, w, l), 1)
  }
  // peeled final iteration (kt 14,15): ph1 drains kt15 fully with vmcnt(0)
  PH(0,     16384, 0, true,  stageAH(Ag, m0, 15, tA, w, l), 0)
  PH(0,     16384, 1, false, , 2)
  PH(32768, 49152, 0, true,  , 0)
  PH(32768, 49152, 1, false, , 0)

  // ---- epilogue: bias + cached scalar stores + per-row sum(exp) ----
  float rsum[4][4];
#pragma unroll
  for (int mi = 0; mi < 4; ++mi)
#pragma unroll
    for (int r = 0; r < 4; ++r) rsum[mi][r] = 0.f;

#pragma unroll
  for (int ni = 0; ni < 2; ++ni) {
    int v = n0 + wc * 32 + ni * 16 + l15;
    float bv = bias[v];
#pragma unroll
    for (int mi = 0; mi < 4; ++mi) {
#pragma unroll
      for (int r = 0; r < 4; ++r) {
        float x = acc[mi][ni][r] + bv;
        int row = m0 + wr * 64 + mi * 16 + kq * 4 + r;   // row = t*64+b
        size_t off = (size_t)(row & 63) * (TSTEPS * (size_t)VOCAB)
                   + (size_t)(row >> 6) * VOCAB + v;
        out[off] = x;
        rsum[mi][r] += __expf(x);
      }
    }
  }
#pragma unroll
  for (int mask = 1; mask < 16; mask <<= 1)
#pragma unroll
    for (int mi = 0; mi < 4; ++mi)
#pragma unroll
      for (int r = 0; r < 4; ++r)
        rsum[mi][r] += __shfl_xor(rsum[mi][r], mask);

  float* ssum = (float*)sm;                          // staging LDS dead now
  __builtin_amdgcn_s_barrier();
  if (l15 == 0) {
#pragma unroll
    for (int mi = 0; mi < 4; ++mi)
#pragma unroll
      for (int r = 0; r < 4; ++r)
        ssum[(wr * 64 + mi * 16 + kq * 4 + r) * 4 + wc] = rsum[mi][r];
  }
  __builtin_amdgcn_s_barrier();
  if (tid < 128) {
    float t4 = ssum[tid * 4] + ssum[tid * 4 + 1] + ssum[tid * 4 + 2] + ssum[tid * 4 + 3];
    px[(size_t)(m0 + tid) * 256 + (n0 >> 7)] = t4;
  }
}

// ---- fused lse-reduce + subtract (one read+write pass over logits) ----
__global__ __launch_bounds__(256) void lsefin_kernel(
    const float* __restrict__ px, float* __restrict__ out) {
  const int tid = threadIdx.x;
  const int b = blockIdx.x >> 6, t = blockIdx.x & 63;   // out row = [b][t]
  const float* p = px + (size_t)(t * 64 + b) * 256;
  float s = (tid < 250) ? p[tid] : 0.f;
#pragma unroll
  for (int off = 1; off < 64; off <<= 1) s += __shfl_xor(s, off);
  __shared__ float ss[4];
  if ((tid & 63) == 0) ss[tid >> 6] = s;
  __syncthreads();
  float lse = logf(ss[0] + ss[1] + ss[2] + ss[3]);
  float* row = out + (size_t)blockIdx.x * VOCAB;
  for (int i = tid * 4; i < VOCAB; i += 1024) {
    f32x4 x = *(const f32x4*)(row + i);
    x[0] -= lse; x[1] -= lse; x[2] -= lse; x[3] -= lse;
    __builtin_nontemporal_store(x, (f32x4*)(row + i));
  }
}

__global__ void hcopy_kernel(const float* __restrict__ h, float* __restrict__ out) {
  int i = blockIdx.x * blockDim.x + threadIdx.x;
  ((float4*)out)[i] = ((const float4*)h)[i];
}

extern "C" void kernel_launch(void* const* d_in, const int* in_sizes, int n_in,
                              void* d_out, int out_size, void* d_ws, size_t ws_size,
                              hipStream_t stream) {
  const float* enc_hidden = (const float*)d_in[1];   // [1,64,1024]
  const int* tgt          = (const int*)d_in[2];     // [64,64]
  const float* emb        = (const float*)d_in[3];   // [32000,1024]
  const float* W_ih       = (const float*)d_in[4];   // [3072,1024]
  const float* W_hh       = (const float*)d_in[5];   // [3072,1024]
  const float* b_ih       = (const float*)d_in[6];   // [3072]
  const float* b_hh       = (const float*)d_in[7];   // [3072]
  const float* W_out      = (const float*)d_in[8];   // [32000,1024]
  const float* b_out      = (const float*)d_in[9];   // [32000]
  float* out = (float*)d_out;

  char* ws = (char*)d_ws;
  // region [0, 65536000): gi (50.3 MB, live through recurrence) then Wout_b (cast after)
  float*    gi     = (float*)(ws);
  uint16_t* Wout_b = (uint16_t*)(ws);
  uint16_t* Wih_b  = (uint16_t*)(ws + 65536000);      // 6,291,456
  uint16_t* Whh_b  = (uint16_t*)(ws + 71827456);      // 6,291,456
  uint16_t* Xb     = (uint16_t*)(ws + 78118912);      // 8,388,608 (reused as px after gi_gemm)
  float*    px     = (float*)   (ws + 78118912);      // [4096][256] f32 = 4,194,304
  uint16_t* Hsb    = (uint16_t*)(ws + 86507520);      // 8,519,680  [65][64][1024]
  float*    hA     = (float*)   (ws + 95027200);      // 262,144
  float*    hB     = (float*)   (ws + 95289344);      // 262,144  (total 95,551,488)

  hipFuncSetAttribute((const void*)out_gemm_kernel,
                      hipFuncAttributeMaxDynamicSharedMemorySize, 65536);

  cast_bf16_kernel<<<2048, 256, 0, stream>>>(W_ih, Wih_b, 3072 * 1024 / 4);
  cast_bf16_kernel<<<2048, 256, 0, stream>>>(W_hh, Whh_b, 3072 * 1024 / 4);
  embed_kernel<<<4096, 256, 0, stream>>>(emb, tgt, Xb);
  h0_kernel<<<64, 256, 0, stream>>>(enc_hidden, Hsb);

  dim3 gg(24, 32);
  gi_gemm_kernel<<<gg, 256, 0, stream>>>(Xb, Wih_b, b_ih, gi);

  for (int t = 0; t < TSTEPS; ++t) {
    const float* hc = (t == 0) ? enc_hidden : ((t & 1) ? hA : hB);
    float* hn       = (t & 1) ? hB : hA;
    step_kernel<<<256, 64, 0, stream>>>(Whh_b, gi, b_hh, hc, hn, Hsb, t);
  }

  cast_bf16_kernel<<<2048, 256, 0, stream>>>(W_out, Wout_b, VOCAB * 1024 / 4);

  dim3 g(1000, 8);
  out_gemm_kernel<<<g, 512, 65536, stream>>>(Hsb + 65536, Wout_b, b_out, out, px);
  lsefin_kernel<<<4096, 256, 0, stream>>>(px, out);
  hcopy_kernel<<<64, 256, 0, stream>>>((TSTEPS & 1) ? hB : hA, out + 131072000ull);
}

// Round 14
// 984.031 us; speedup vs baseline: 1.1699x; 1.1699x over previous
//
#include <hip/hip_runtime.h>
#include <hip/hip_bf16.h>
#include <stdint.h>

#define H 1024
#define BATCH 64
#define TSTEPS 64
#define VOCAB 32000

typedef __attribute__((ext_vector_type(8))) short bf16x8;
typedef __attribute__((ext_vector_type(4))) float f32x4;

__device__ __forceinline__ uint16_t f2b(float f) {
  union { float f; uint32_t u; } v; v.f = f;
  uint32_t u = v.u;
  return (uint16_t)((u + 0x7FFFu + ((u >> 16) & 1u)) >> 16);
}

__device__ __forceinline__ void g2l16(const uint16_t* g, uint16_t* l) {
  __builtin_amdgcn_global_load_lds((const __attribute__((address_space(1))) void*)(g),
                                   (__attribute__((address_space(3))) void*)(l), 16, 0, 0);
}

// ---- f32 -> bf16 cast (n4 = n/4) ----
__global__ void cast_bf16_kernel(const float* __restrict__ src, uint16_t* __restrict__ dst, int n4) {
  int i = blockIdx.x * blockDim.x + threadIdx.x;
  int stride = gridDim.x * blockDim.x;
  for (; i < n4; i += stride) {
    float4 f = ((const float4*)src)[i];
    union { uint16_t u[4]; uint64_t d; } o;
    o.u[0] = f2b(f.x); o.u[1] = f2b(f.y); o.u[2] = f2b(f.z); o.u[3] = f2b(f.w);
    ((uint64_t*)dst)[i] = o.d;
  }
}

// ---- embed + relu -> bf16, X[t*64+b][H] ----
__global__ void embed_kernel(const float* __restrict__ emb, const int* __restrict__ tgt,
                             uint16_t* __restrict__ X) {
  int i = blockIdx.x;            // 0..4095 = t*64+b
  int t = i >> 6, b = i & 63;
  int tok = (t == 0) ? 0 : tgt[b * TSTEPS + (t - 1)];
  const float4* src = (const float4*)(emb + (size_t)tok * H);
  uint64_t* dst = (uint64_t*)(X + (size_t)i * H);
  int k = threadIdx.x;           // 256 threads x 4 elems
  float4 f = src[k];
  union { uint16_t u[4]; uint64_t d; } o;
  o.u[0] = f2b(fmaxf(f.x, 0.f)); o.u[1] = f2b(fmaxf(f.y, 0.f));
  o.u[2] = f2b(fmaxf(f.z, 0.f)); o.u[3] = f2b(fmaxf(f.w, 0.f));
  dst[k] = o.d;
}

// ---- h0 init: cast enc_hidden to bf16 into Hsb[0] ----
__global__ void h0_kernel(const float* __restrict__ eh, uint16_t* __restrict__ hb0) {
  int i = blockIdx.x * blockDim.x + threadIdx.x;   // 16384 threads x 4
  float4 f = ((const float4*)eh)[i];
  union { uint16_t u[4]; uint64_t d; } o;
  o.u[0] = f2b(f.x); o.u[1] = f2b(f.y); o.u[2] = f2b(f.z); o.u[3] = f2b(f.w);
  ((uint64_t*)hb0)[i] = o.d;
}

// ---- gi GEMM: gi = relu(emb)@W_ih^T + b_ih, row-major [4096][3072] f32 ----
__global__ __launch_bounds__(256) void gi_gemm_kernel(
    const uint16_t* __restrict__ A,    // [4096][1024]
    const uint16_t* __restrict__ Bm,   // [3072][1024]
    const float* __restrict__ bias,    // [3072]
    float* __restrict__ out) {         // [4096][3072]
  __shared__ uint16_t lA[128 * 32];
  __shared__ uint16_t lB[128 * 32];
  const int tid = threadIdx.x;
  const int lane = tid & 63;
  const int w = tid >> 6;
  const int wr = w >> 1, wc = w & 1;
  int flat = blockIdx.y * 24 + blockIdx.x;       // 768 blocks
  int nf = (flat & 7) * 96 + (flat >> 3);        // XCD swizzle (768 % 8 == 0)
  const int m0 = (nf / 24) * 128;
  const int n0 = (nf % 24) * 128;

  f32x4 acc[4][4];
#pragma unroll
  for (int mi = 0; mi < 4; ++mi)
#pragma unroll
    for (int ni = 0; ni < 4; ++ni) acc[mi][ni] = (f32x4){0, 0, 0, 0};

  const int srow = w * 16 + (lane >> 2);
  const int scol = (lane & 3) * 8;

  for (int k0 = 0; k0 < 1024; k0 += 32) {
    __syncthreads();
    g2l16(A + (size_t)(m0 + srow) * 1024 + k0 + scol,       &lA[w * 512]);
    g2l16(A + (size_t)(m0 + 64 + srow) * 1024 + k0 + scol,  &lA[2048 + w * 512]);
    g2l16(Bm + (size_t)(n0 + srow) * 1024 + k0 + scol,      &lB[w * 512]);
    g2l16(Bm + (size_t)(n0 + 64 + srow) * 1024 + k0 + scol, &lB[2048 + w * 512]);
    __syncthreads();
    bf16x8 a[4], b[4];
#pragma unroll
    for (int mi = 0; mi < 4; ++mi)
      a[mi] = *(const bf16x8*)&lA[(wr * 64 + mi * 16 + (lane & 15)) * 32 + (lane >> 4) * 8];
#pragma unroll
    for (int ni = 0; ni < 4; ++ni)
      b[ni] = *(const bf16x8*)&lB[(wc * 64 + ni * 16 + (lane & 15)) * 32 + (lane >> 4) * 8];
#pragma unroll
    for (int mi = 0; mi < 4; ++mi)
#pragma unroll
      for (int ni = 0; ni < 4; ++ni)
        acc[mi][ni] = __builtin_amdgcn_mfma_f32_16x16x32_bf16(a[mi], b[ni], acc[mi][ni], 0, 0, 0);
  }

#pragma unroll
  for (int ni = 0; ni < 4; ++ni) {
    int v = n0 + wc * 64 + ni * 16 + (lane & 15);
    float bv = bias[v];
#pragma unroll
    for (int mi = 0; mi < 4; ++mi) {
#pragma unroll
      for (int r = 0; r < 4; ++r) {
        int row = m0 + wr * 64 + mi * 16 + (lane >> 4) * 4 + r;
        out[(size_t)row * 3072 + v] = acc[mi][ni][r] + bv;
      }
    }
  }
}

// ---- one GRU step, gh-only: 256 blocks x 64 threads (R4 proven shape) ----
__global__ __launch_bounds__(64) void step_kernel(
    const uint16_t* __restrict__ Whh_b,  // [3072][1024] bf16
    const float* __restrict__ gi,        // [4096][3072] f32 (incl b_ih)
    const float* __restrict__ b_hh,      // [3072]
    const float* __restrict__ h_cur,     // [64][1024] f32
    float* __restrict__ h_nxt,           // [64][1024] f32
    uint16_t* __restrict__ Hsb,          // [65][64][1024] bf16
    int t) {
  const int lane = threadIdx.x;
  const int l15 = lane & 15, kq = lane >> 4;
  const int rg = blockIdx.x >> 6, cs = blockIdx.x & 63;
  const int m0 = rg * 16, c0 = cs * 16;
  const int c = c0 + l15;

  float gr[4], gz[4], gn[4], hold[4];
#pragma unroll
  for (int r = 0; r < 4; ++r) {
    int m = m0 + kq * 4 + r;
    const float* gp = gi + (size_t)(t * 64 + m) * 3072;
    gr[r] = gp[c]; gz[r] = gp[1024 + c]; gn[r] = gp[2048 + c];
    hold[r] = h_cur[(size_t)m * 1024 + c];
  }

  const uint16_t* ap = Hsb + (size_t)(t * 64 + m0 + l15) * 1024 + kq * 8;
  const uint16_t* br = Whh_b + (size_t)(c) * 1024 + kq * 8;
  const uint16_t* bz = Whh_b + (size_t)(1024 + c) * 1024 + kq * 8;
  const uint16_t* bn = Whh_b + (size_t)(2048 + c) * 1024 + kq * 8;

  f32x4 ar = {0,0,0,0}, az = {0,0,0,0}, an = {0,0,0,0};
#pragma unroll
  for (int kk = 0; kk < 32; ++kk) {
    bf16x8 a = *(const bf16x8*)(ap + kk * 32);
    ar = __builtin_amdgcn_mfma_f32_16x16x32_bf16(a, *(const bf16x8*)(br + kk * 32), ar, 0, 0, 0);
    az = __builtin_amdgcn_mfma_f32_16x16x32_bf16(a, *(const bf16x8*)(bz + kk * 32), az, 0, 0, 0);
    an = __builtin_amdgcn_mfma_f32_16x16x32_bf16(a, *(const bf16x8*)(bn + kk * 32), an, 0, 0, 0);
  }

  float bhr = b_hh[c], bhz = b_hh[1024 + c], bhn = b_hh[2048 + c];
#pragma unroll
  for (int r = 0; r < 4; ++r) {
    int m = m0 + kq * 4 + r;
    float rg_ = 1.f / (1.f + __expf(-(gr[r] + ar[r] + bhr)));
    float zg  = 1.f / (1.f + __expf(-(gz[r] + az[r] + bhz)));
    float ng  = tanhf(gn[r] + rg_ * (an[r] + bhn));
    float hnew = (1.f - zg) * ng + zg * hold[r];
    h_nxt[(size_t)m * 1024 + c] = hnew;
    Hsb[(size_t)((t + 1) * 64 + m) * 1024 + c] = f2b(hnew);
  }
}

// ================= 256x256 8-phase out-GEMM (T2+T3+T4+T5) =================
// vmcnt ledger: steady-state ph3/ph7 have 14 in flight; vmcnt(6) retires 8 =
// exactly the next-needed K-tile. Last iteration peeled with vmcnt(0) (R7 race).
// Epilogue: acc -> LDS (kq-XOR swizzle, 2 halves of 128x256) -> coalesced
// f32x4 NT stores + per-row exp-sum (one wave covers a full 256-col row).
// [R14: restored R9 verbatim — measured best total 987 µs; epilogue matrix
// R9/R10/R11/R13 shows f32x4-NT@1blk/CU is the clean-write optimum.]

__device__ __forceinline__ void stageAH(const uint16_t* __restrict__ G, int grow0, int kt,
                                        char* lbase, int w, int l) {
#pragma unroll
  for (int j = 0; j < 2; ++j) {
    int c = w * 2 + j;
    int r = c * 8 + (l >> 3);
    int scol = ((l & 7) ^ (l >> 3)) * 8;   // pre-swizzled global col-slot
    g2l16(G + (size_t)(grow0 + r) * 1024 + kt * 64 + scol, (uint16_t*)(lbase + c * 1024));
  }
}

template<int D, int MP, bool RB>
__device__ __forceinline__ void ph_read(const char* sm, int wr, int wc, int l15, int kq,
                                        bf16x8 (&afr)[2][2], bf16x8 (&bfr)[4][2]) {
#pragma unroll
  for (int m = 0; m < 2; ++m) {
    const int mi = MP * 2 + m;
    const int h = mi >> 2;
    const int r = wr * 64 + (mi & 3) * 16 + l15;
    const char* base = sm + D * 65536 + h * 16384 + r * 128;
#pragma unroll
    for (int ks = 0; ks < 2; ++ks)
      afr[m][ks] = *(const bf16x8*)(base + ((((ks << 2) + kq) ^ (r & 7)) << 4));
  }
  if constexpr (RB) {
#pragma unroll
    for (int ni = 0; ni < 4; ++ni) {
      const int r = (wc & 1) * 64 + ni * 16 + l15;
      const char* base = sm + D * 65536 + 32768 + (wc >> 1) * 16384 + r * 128;
#pragma unroll
      for (int ks = 0; ks < 2; ++ks)
        bfr[ni][ks] = *(const bf16x8*)(base + ((((ks << 2) + kq) ^ (r & 7)) << 4));
    }
  }
}

template<int MP>
__device__ __forceinline__ void ph_mma(f32x4 (&acc)[8][4], bf16x8 (&afr)[2][2], bf16x8 (&bfr)[4][2]) {
  __builtin_amdgcn_s_setprio(1);
#pragma unroll
  for (int m = 0; m < 2; ++m)
#pragma unroll
    for (int ni = 0; ni < 4; ++ni)
#pragma unroll
      for (int ks = 0; ks < 2; ++ks)
        acc[MP * 2 + m][ni] =
            __builtin_amdgcn_mfma_f32_16x16x32_bf16(afr[m][ks], bfr[ni][ks], acc[MP * 2 + m][ni], 0, 0, 0);
  __builtin_amdgcn_s_setprio(0);
}

// VM: 0 = no wait, 1 = vmcnt(6) (steady state), 2 = vmcnt(0) (final drain)
#define PHX(D, MP, RB, STG, VM) { \
  bf16x8 afr[2][2]; \
  ph_read<D, MP, RB>(sm, wr, wc, l15, kq, afr, bfr); \
  STG; \
  __builtin_amdgcn_sched_barrier(0); \
  if (VM == 1) asm volatile("s_waitcnt vmcnt(6)" ::: "memory"); \
  if (VM == 2) asm volatile("s_waitcnt vmcnt(0)" ::: "memory"); \
  __builtin_amdgcn_s_barrier(); \
  ph_mma<MP>(acc, afr, bfr); \
  __builtin_amdgcn_s_barrier(); \
}

__global__ __launch_bounds__(512, 1) void out_gemm_kernel(
    const uint16_t* __restrict__ Ag,   // [4096][1024]  (Hsb+65536)
    const uint16_t* __restrict__ Bg,   // [32000][1024]
    const float* __restrict__ bias,    // [32000]
    float* __restrict__ out,
    float* __restrict__ px) {          // [4096][128] sum-exp per 256-col block
  extern __shared__ char sm[];
  const int tid = threadIdx.x;
  const int l = tid & 63, w = tid >> 6;
  const int l15 = l & 15, kq = l >> 4;
  const int wr = w >> 2, wc = w & 3;
  // 2D-chunked XCD mapping: 2000 blocks, xcd owns 2 m-tiles, sweeps 125 n-tiles
  int flat = blockIdx.y * 250 + blockIdx.x;
  int xcd = flat & 7, i0 = flat >> 3;            // i0 in 0..249
  const int m0 = ((xcd << 1) | (i0 & 1)) * 256;  // m-tile 0..15
  const int n0 = (i0 >> 1) * 256;                // n-tile 0..124

  char* const sA0 = sm;
  char* const sA1 = sm + 16384;
  char* const sB0 = sm + 32768;
  char* const sB1 = sm + 49152;
  char* const tA0 = sm + 65536;
  char* const tA1 = sm + 81920;
  char* const tB0 = sm + 98304;
  char* const tB1 = sm + 114688;

  f32x4 acc[8][4];
#pragma unroll
  for (int mi = 0; mi < 8; ++mi)
#pragma unroll
    for (int ni = 0; ni < 4; ++ni) acc[mi][ni] = (f32x4){0, 0, 0, 0};

  // prologue: kt0 fully + kt1 (B0,B1,A0); kt1's A1 staged in ph0 of iter 0
  stageAH(Bg, n0,       0, sB0, w, l);
  stageAH(Bg, n0 + 128, 0, sB1, w, l);
  stageAH(Ag, m0,       0, sA0, w, l);
  stageAH(Ag, m0 + 128, 0, sA1, w, l);
  stageAH(Bg, n0,       1, tB0, w, l);
  stageAH(Bg, n0 + 128, 1, tB1, w, l);
  stageAH(Ag, m0,       1, tA0, w, l);
  asm volatile("s_waitcnt vmcnt(6)" ::: "memory");   // kt0's 8 loads retired
  __builtin_amdgcn_s_barrier();

  bf16x8 bfr[4][2];
  for (int i = 0; i < 7; ++i) {                      // steady-state iters (kt 2i,2i+1)
    PHX(0, 0, true,  stageAH(Ag, m0 + 128, 2 * i + 1, tA1, w, l), 0)
    PHX(0, 1, false, stageAH(Bg, n0,       2 * i + 2, sB0, w, l), 0)
    PHX(0, 2, false, stageAH(Bg, n0 + 128, 2 * i + 2, sB1, w, l), 0)
    PHX(0, 3, false, stageAH(Ag, m0,       2 * i + 2, sA0, w, l), 1)
    PHX(1, 0, true,  stageAH(Ag, m0 + 128, 2 * i + 2, sA1, w, l), 0)
    PHX(1, 1, false, stageAH(Bg, n0,       2 * i + 3, tB0, w, l), 0)
    PHX(1, 2, false, stageAH(Bg, n0 + 128, 2 * i + 3, tB1, w, l), 0)
    PHX(1, 3, false, stageAH(Ag, m0,       2 * i + 3, tA0, w, l), 1)
  }
  // peeled final iteration (kt 14,15): vmcnt(0) at ph3 drains all of kt15
  PHX(0, 0, true,  stageAH(Ag, m0 + 128, 15, tA1, w, l), 0)
  PHX(0, 1, false, , 0)
  PHX(0, 2, false, , 0)
  PHX(0, 3, false, , 2)
  PHX(1, 0, true,  , 0)
  PHX(1, 1, false, , 0)
  PHX(1, 2, false, , 0)
  PHX(1, 3, false, , 0)

  // ---- epilogue: LDS transpose -> coalesced f32x4 NT stores + exp-sum ----
  float* eb = (float*)sm;                            // [128][256] f32 = 128 KiB
#pragma unroll
  for (int half = 0; half < 2; ++half) {
    // write this half's acc quadrants; col XOR kq<<4 => 2-way bank alias (free)
#pragma unroll
    for (int mi = 0; mi < 4; ++mi) {
      int RL0 = wr * 64 + mi * 16 + kq * 4;
#pragma unroll
      for (int r = 0; r < 4; ++r)
#pragma unroll
        for (int ni = 0; ni < 4; ++ni) {
          int col = wc * 64 + ni * 16 + l15;
          eb[(RL0 + r) * 256 + (col ^ (kq << 4))] = acc[half * 4 + mi][ni][r];
        }
    }
    __builtin_amdgcn_s_barrier();
    // read back linearly: wave w covers rows w, w+8, ... (full 256-col row/wave)
#pragma unroll
    for (int j = 0; j < 16; ++j) {
      int RL = w + j * 8;
      int c4 = l * 4;
      int cs4 = c4 ^ (((RL >> 2) & 3) << 4);
      f32x4 v = *(const f32x4*)(eb + RL * 256 + cs4);
      float4 bv = *(const float4*)(bias + n0 + c4);
      f32x4 x = {v[0] + bv.x, v[1] + bv.y, v[2] + bv.z, v[3] + bv.w};
      int Rg = m0 + half * 128 + RL;                 // row = t*64+b
      size_t off = (size_t)(Rg & 63) * (TSTEPS * (size_t)VOCAB)
                 + (size_t)(Rg >> 6) * VOCAB + n0 + c4;
      __builtin_nontemporal_store(x, (f32x4*)(out + off));
      float es = __expf(x[0]) + __expf(x[1]) + __expf(x[2]) + __expf(x[3]);
#pragma unroll
      for (int m = 1; m < 64; m <<= 1) es += __shfl_xor(es, m);
      if (l == 0) px[(size_t)Rg * 128 + (n0 >> 8)] = es;
    }
    __builtin_amdgcn_s_barrier();
  }
}

// ---- fused lse-reduce + subtract (one read+write pass over logits) ----
__global__ __launch_bounds__(256) void lsefin_kernel(
    const float* __restrict__ px, float* __restrict__ out) {
  const int tid = threadIdx.x;
  const int b = blockIdx.x >> 6, t = blockIdx.x & 63;   // out row = [b][t]
  const float* p = px + (size_t)(t * 64 + b) * 128;
  float s = (tid < 125) ? p[tid] : 0.f;
#pragma unroll
  for (int off = 1; off < 64; off <<= 1) s += __shfl_xor(s, off);
  __shared__ float ss[4];
  if ((tid & 63) == 0) ss[tid >> 6] = s;
  __syncthreads();
  float lse = logf(ss[0] + ss[1] + ss[2] + ss[3]);
  float* row = out + (size_t)blockIdx.x * VOCAB;
  for (int i = tid * 4; i < VOCAB; i += 1024) {
    f32x4 x = __builtin_nontemporal_load((const f32x4*)(row + i));
    x[0] -= lse; x[1] -= lse; x[2] -= lse; x[3] -= lse;
    __builtin_nontemporal_store(x, (f32x4*)(row + i));
  }
}

__global__ void hcopy_kernel(const float* __restrict__ h, float* __restrict__ out) {
  int i = blockIdx.x * blockDim.x + threadIdx.x;
  ((float4*)out)[i] = ((const float4*)h)[i];
}

extern "C" void kernel_launch(void* const* d_in, const int* in_sizes, int n_in,
                              void* d_out, int out_size, void* d_ws, size_t ws_size,
                              hipStream_t stream) {
  const float* enc_hidden = (const float*)d_in[1];   // [1,64,1024]
  const int* tgt          = (const int*)d_in[2];     // [64,64]
  const float* emb        = (const float*)d_in[3];   // [32000,1024]
  const float* W_ih       = (const float*)d_in[4];   // [3072,1024]
  const float* W_hh       = (const float*)d_in[5];   // [3072,1024]
  const float* b_ih       = (const float*)d_in[6];   // [3072]
  const float* b_hh       = (const float*)d_in[7];   // [3072]
  const float* W_out      = (const float*)d_in[8];   // [32000,1024]
  const float* b_out      = (const float*)d_in[9];   // [32000]
  float* out = (float*)d_out;

  char* ws = (char*)d_ws;
  // region [0, 65536000): gi (50.3 MB, live through recurrence) then Wout_b (cast after)
  float*    gi     = (float*)(ws);
  uint16_t* Wout_b = (uint16_t*)(ws);
  uint16_t* Wih_b  = (uint16_t*)(ws + 65536000);      // 6,291,456
  uint16_t* Whh_b  = (uint16_t*)(ws + 71827456);      // 6,291,456
  uint16_t* Xb     = (uint16_t*)(ws + 78118912);      // 8,388,608 (reused as px after gi_gemm)
  float*    px     = (float*)   (ws + 78118912);      // [4096][128] f32 = 2,097,152
  uint16_t* Hsb    = (uint16_t*)(ws + 86507520);      // 8,519,680  [65][64][1024]
  float*    hA     = (float*)   (ws + 95027200);      // 262,144
  float*    hB     = (float*)   (ws + 95289344);      // 262,144  (total 95,551,488)

  hipFuncSetAttribute((const void*)out_gemm_kernel,
                      hipFuncAttributeMaxDynamicSharedMemorySize, 131072);

  cast_bf16_kernel<<<2048, 256, 0, stream>>>(W_ih, Wih_b, 3072 * 1024 / 4);
  cast_bf16_kernel<<<2048, 256, 0, stream>>>(W_hh, Whh_b, 3072 * 1024 / 4);
  embed_kernel<<<4096, 256, 0, stream>>>(emb, tgt, Xb);
  h0_kernel<<<64, 256, 0, stream>>>(enc_hidden, Hsb);

  dim3 gg(24, 32);
  gi_gemm_kernel<<<gg, 256, 0, stream>>>(Xb, Wih_b, b_ih, gi);

  for (int t = 0; t < TSTEPS; ++t) {
    const float* hc = (t == 0) ? enc_hidden : ((t & 1) ? hA : hB);
    float* hn       = (t & 1) ? hB : hA;
    step_kernel<<<256, 64, 0, stream>>>(Whh_b, gi, b_hh, hc, hn, Hsb, t);
  }

  cast_bf16_kernel<<<2048, 256, 0, stream>>>(W_out, Wout_b, VOCAB * 1024 / 4);

  dim3 g(250, 8);
  out_gemm_kernel<<<g, 512, 131072, stream>>>(Hsb + 65536, Wout_b, b_out, out, px);
  lsefin_kernel<<<4096, 256, 0, stream>>>(px, out);
  hcopy_kernel<<<64, 256, 0, stream>>>((TSTEPS & 1) ? hB : hA, out + 131072000ull);
}